// Round 15
// baseline (62.289 us; speedup 1.0000x reference)
//
#include <hip/hip_runtime.h>
#include <hip/hip_bf16.h>

typedef __bf16 bf16x8 __attribute__((ext_vector_type(8)));
typedef __bf16 bf16x4 __attribute__((ext_vector_type(4)));
typedef __bf16 bf16x2 __attribute__((ext_vector_type(2)));
typedef float  f32x4  __attribute__((ext_vector_type(4)));
typedef float  f32x2  __attribute__((ext_vector_type(2)));

constexpr int kD  = 512;
constexpr int kBD = 64;
constexpr int kN  = 4096;
constexpr int kB  = 8;

// Prep: Wbk/Wbv fp32 -> bf16 ws images (blocks 0..31); block 32 zeroes S.
__global__ __launch_bounds__(256)
void lbm_prep(const float* __restrict__ Wbk, const float* __restrict__ Wbv,
              __bf16* __restrict__ wsk, __bf16* __restrict__ wsv,
              float* __restrict__ S)
{
    const int bid = blockIdx.x, t = threadIdx.x;
    if (bid < 32) {
        int i = (bid * 256 + t) * 4;
        float4 a = *(const float4*)(Wbk + i);
        float4 b = *(const float4*)(Wbv + i);
        bf16x4 ka, vb;
        ka[0]=(__bf16)a.x; ka[1]=(__bf16)a.y; ka[2]=(__bf16)a.z; ka[3]=(__bf16)a.w;
        vb[0]=(__bf16)b.x; vb[1]=(__bf16)b.y; vb[2]=(__bf16)b.z; vb[3]=(__bf16)b.w;
        *(bf16x4*)(wsk + i) = ka;
        *(bf16x4*)(wsv + i) = vb;
    } else {
        S[t * 2] = 0.f; S[t * 2 + 1] = 0.f;
    }
}

// Pass 1: kp[row,j] = keys[row,:].Wbk[j,:] + bbk[j]  (arr = bid&1 picks K/V).
// R13's at-ceiling engine (2 blocks/CU, probe-shaped loads, 3-deep counted
// vmcnt, lgkmcnt-only barriers) x 4 row-tiles per block: weight restaging
// 134 -> 33.5 MB. 512 blocks x 1024 thr; LDS = 64K weights + 8K data dbuf
// + 8K red = 80 KB -> exactly 2 blocks/CU (32 waves/CU max).
__global__ __launch_bounds__(1024, 8)
void lbm_proj(const float* __restrict__ keys, const float* __restrict__ values,
              const __bf16* __restrict__ wsk, const __bf16* __restrict__ wsv,
              const float* __restrict__ bbk,  const float* __restrict__ bbv,
              float* __restrict__ kp,         float* __restrict__ vp)
{
    __shared__ __align__(16) __bf16 ldsW[kBD * kD];    // swizzled weights, 64 KB
    __shared__ __align__(16) __bf16 ldsD[2][32 * 64];  // data dbuf bf16, 8 KB
    __shared__ __align__(16) f32x4  red[8 * 64];       // dgrp0 publish, 8 KB

    const int tid = threadIdx.x;
    const int w   = tid >> 6;
    const int ln  = tid & 63;
    const int l15 = ln & 15;
    const int lhi = ln >> 4;
    const int sw7 = l15 & 7;
    const int chunk = w & 1;            // 16-row chunk of the staged 32 rows
    const int jt    = (w >> 1) & 3;     // j-tile
    const int dgrp  = w >> 3;           // d-half (0: phases 0-3 of tile, 1: 4-7)
    const int role8 = w & 7;

    const int bid = blockIdx.x;
    const int arr = bid & 1;
    const int t0  = bid >> 1;                       // 0..255
    const int swz = (t0 & 7) * 32 + (t0 >> 3);      // XCD-bijective
    const int rows0 = swz * 128;                    // 4 tiles x 32 rows

    const float*  src  = arr ? values : keys;
    const __bf16* wsrc = arr ? wsv    : wsk;
    const float*  bsrc = arr ? bbv    : bbk;
    float*        dst  = arr ? vp     : kp;

    // data staging: thread owns 2 floats/phase; contiguous 256B per row-group
    const int srow = tid >> 5;                      // 0..31
    const float* sbase = src + (size_t)(rows0 + srow) * kD + (tid & 31) * 2;
    const int wel = srow * 64 + ((((tid & 31) >> 2) ^ (srow & 7)) << 3) + (tid & 3) * 2;

#define LOADD(sl, t_, dph_)                                                   \
    asm volatile("global_load_dwordx2 %0, %1, off offset:%c2"                 \
                 : "=v"(sl) : "v"(sbase + (t_) * (32 * kD)), "i"((dph_) * 256));
#define WAITD(sl, n)                                                          \
    asm volatile("s_waitcnt vmcnt(%c1)" : "+v"(sl) : "i"(n));

    f32x2 s0, s1, s2;
#define SLOT(q) ((q) % 3 == 0 ? s0 : ((q) % 3 == 1 ? s1 : s2))

    LOADD(s0, 0, 0) LOADD(s1, 0, 1) LOADD(s2, 0, 2)   // data loads FIRST (oldest)

    // ---- weight staging: 64KB image -> XOR-swizzled LDS ----
    #pragma unroll
    for (int i = 0; i < 4; ++i) {
        int G = i * 1024 + tid;              // granule16 0..4095
        int j = G >> 6, c = G & 63;
        *(bf16x8*)&ldsW[j * kD + ((c ^ (j & 7)) << 3)] = *(const bf16x8*)(wsrc + G * 8);
    }
    const float bias = bsrc[jt * 16 + l15];

    // phase-0 write (retire-6-of-8 analysis: s0 guaranteed complete; R13-proven)
    WAITD(s0, 2)
    { bf16x2 t2; t2[0] = (__bf16)s0[0]; t2[1] = (__bf16)s0[1];
      *(bf16x2*)&ldsD[0][wel] = t2; }
    __syncthreads();   // one-time prologue drain

    f32x4 acc = {0.f, 0.f, 0.f, 0.f};

    // phase p (0..31): tile = p>>3, d-phase pp = p&7.
    // [issue p+3] [2 MFMAs if our d-half] [wait p+1, cvt+write] [barrier]
    // tile end (pp==7): dgrp0 publish -> barrier -> dgrp1 merge+bias -> dst.
#define PHASE(p_, waitn_)                                                     \
    {                                                                         \
        if ((p_) + 3 < 32) { LOADD(SLOT((p_) + 3), (((p_) + 3) >> 3), (((p_) + 3) & 7)) } \
        if (dgrp == ((((p_) & 7)) >> 2)) {                                    \
            _Pragma("unroll")                                                 \
            for (int ks = 0; ks < 2; ++ks) {                                  \
                bf16x8 af = *(const bf16x8*)&ldsD[(p_) & 1]                   \
                    [(chunk * 16 + l15) * 64 + (((ks * 4 + lhi) ^ sw7) << 3)];\
                bf16x8 wf = *(const bf16x8*)&ldsW                             \
                    [(jt * 16 + l15) * kD + (((((p_) & 7) * 8 + ks * 4 + lhi) ^ sw7) << 3)]; \
                acc = __builtin_amdgcn_mfma_f32_16x16x32_bf16(af, wf, acc, 0, 0, 0); \
            }                                                                 \
        }                                                                     \
        if ((p_) + 1 < 32) {                                                  \
            WAITD(SLOT((p_) + 1), waitn_)                                     \
            bf16x2 t2; t2[0] = (__bf16)SLOT((p_) + 1)[0];                     \
            t2[1] = (__bf16)SLOT((p_) + 1)[1];                                \
            *(bf16x2*)&ldsD[((p_) + 1) & 1][wel] = t2;                        \
        }                                                                     \
        asm volatile("s_waitcnt lgkmcnt(0)" ::: "memory");                    \
        __builtin_amdgcn_s_barrier();                                         \
        if (((p_) & 7) == 7) {                                                \
            if (dgrp == 0) red[role8 * 64 + ln] = acc;                        \
            asm volatile("s_waitcnt lgkmcnt(0)" ::: "memory");                \
            __builtin_amdgcn_s_barrier();                                     \
            if (dgrp == 1) {                                                  \
                f32x4 o = red[role8 * 64 + ln];                               \
                _Pragma("unroll")                                             \
                for (int i = 0; i < 4; ++i)                                   \
                    dst[(size_t)(rows0 + ((p_) >> 3) * 32 + chunk * 16 + lhi * 4 + i) * kBD \
                        + jt * 16 + l15] = acc[i] + o[i] + bias;              \
            }                                                                 \
            acc[0] = 0.f; acc[1] = 0.f; acc[2] = 0.f; acc[3] = 0.f;           \
        }                                                                     \
    }

    PHASE(0, 2)  PHASE(1, 2)  PHASE(2, 2)  PHASE(3, 2)
    PHASE(4, 2)  PHASE(5, 2)  PHASE(6, 2)  PHASE(7, 2)
    PHASE(8, 2)  PHASE(9, 2)  PHASE(10, 2) PHASE(11, 2)
    PHASE(12, 2) PHASE(13, 2) PHASE(14, 2) PHASE(15, 2)
    PHASE(16, 2) PHASE(17, 2) PHASE(18, 2) PHASE(19, 2)
    PHASE(20, 2) PHASE(21, 2) PHASE(22, 2) PHASE(23, 2)
    PHASE(24, 2) PHASE(25, 2) PHASE(26, 2) PHASE(27, 2)
    PHASE(28, 2) PHASE(29, 1) PHASE(30, 0) PHASE(31, 0)
#undef PHASE
#undef SLOT
#undef LOADD
#undef WAITD
}

// Pass 2: S[b,j] = sum_rows kp[row,j] * vp[row,j]. 512 blocks x 64 rows, f32x4.
__global__ __launch_bounds__(256)
void lbm_comb(const float* __restrict__ kp, const float* __restrict__ vp,
              float* __restrict__ S)
{
    const int t  = threadIdx.x;
    const int j4 = t & 15;          // 16 x f32x4 = 64 j
    const int rg = t >> 4;          // 16 row-groups of 4 rows
    const size_t r0 = (size_t)blockIdx.x * 64 + rg * 4;
    const f32x4* kp4 = (const f32x4*)kp;
    const f32x4* vp4 = (const f32x4*)vp;
    f32x4 acc = {0.f, 0.f, 0.f, 0.f};
    #pragma unroll
    for (int r = 0; r < 4; ++r) {
        size_t idx = (r0 + r) * 16 + j4;
        f32x4 a = kp4[idx], b = vp4[idx];
        acc[0] += a[0]*b[0]; acc[1] += a[1]*b[1];
        acc[2] += a[2]*b[2]; acc[3] += a[3]*b[3];
    }
    __shared__ f32x4 red[16][16];
    red[rg][j4] = acc;
    __syncthreads();
    if (t < 16) {
        f32x4 s = {0.f, 0.f, 0.f, 0.f};
        #pragma unroll
        for (int g = 0; g < 16; ++g) {
            f32x4 v = red[g][t];
            s[0] += v[0]; s[1] += v[1]; s[2] += v[2]; s[3] += v[3];
        }
        int b = (blockIdx.x * 64) >> 12;   // / kN
        atomicAdd(&S[b * kBD + t * 4 + 0], s[0]);
        atomicAdd(&S[b * kBD + t * 4 + 1], s[1]);
        atomicAdd(&S[b * kBD + t * 4 + 2], s[2]);
        atomicAdd(&S[b * kBD + t * 4 + 3], s[3]);
    }
}

// Fused tail: 64 blocks; each block redundantly computes S->Bsum->ms->ext->LN
// for its batch b, then its 64-wide slice of out = normed.Wo^T + bo.
__global__ __launch_bounds__(256)
void lbm_tail(const float* __restrict__ S,    const float* __restrict__ query,
              const float* __restrict__ Wbc,  const float* __restrict__ bbc,
              const float* __restrict__ Wuq,  const float* __restrict__ buq,
              const float* __restrict__ Wue,  const float* __restrict__ bue,
              const float* __restrict__ ln_g, const float* __restrict__ ln_b,
              const float* __restrict__ Wo,   const float* __restrict__ bo,
              float* __restrict__ out)
{
    const int b = blockIdx.x >> 3;
    const int s = blockIdx.x & 7;
    const int t = threadIdx.x;

    __shared__ float shS[kBD];
    __shared__ float shB[kD];
    __shared__ float shMs[kBD];
    __shared__ float shN[kD];
    __shared__ float redT[4][kBD];
    __shared__ float redQ[4][kBD];
    __shared__ float redLN[8];
    __shared__ float s_mu, s_rs;

    if (t < kBD) shS[t] = S[b * kBD + t];
    __syncthreads();

    for (int d = t; d < kD; d += 256) {
        const float4* wr = (const float4*)(Wbc + d * kBD);
        float acc = 0.f;
        #pragma unroll
        for (int q4 = 0; q4 < 16; ++q4) {
            float4 w = wr[q4];
            acc += w.x * shS[q4*4+0] + w.y * shS[q4*4+1]
                 + w.z * shS[q4*4+2] + w.w * shS[q4*4+3];
        }
        shB[d] = acc + (float)kN * bbc[d];
    }
    __syncthreads();

    {
        const int jj = t & 63, qq = t >> 6;
        const float4* wr = (const float4*)(Wuq + jj * kD + qq * 128);
        const float4* qr = (const float4*)(query + b * kD + qq * 128);
        const float4* br = (const float4*)(shB + qq * 128);
        float at = 0.f, aq = 0.f;
        #pragma unroll
        for (int i = 0; i < 32; ++i) {
            float4 w = wr[i]; float4 bb = br[i]; float4 qv = qr[i];
            at += w.x*bb.x + w.y*bb.y + w.z*bb.z + w.w*bb.w;
            aq += w.x*qv.x + w.y*qv.y + w.z*qv.z + w.w*qv.w;
        }
        redT[qq][jj] = at; redQ[qq][jj] = aq;
    }
    __syncthreads();
    if (t < kBD) {
        float tv = redT[0][t] + redT[1][t] + redT[2][t] + redT[3][t] + (float)kN * buq[t];
        float qv = redQ[0][t] + redQ[1][t] + redQ[2][t] + redQ[3][t] + buq[t];
        shMs[t] = tv * qv;
    }
    __syncthreads();

    float lsum = 0.f, lsq = 0.f;
    for (int d = t; d < kD; d += 256) {
        const float4* wr = (const float4*)(Wue + d * kBD);
        float acc = 0.f;
        #pragma unroll
        for (int q4 = 0; q4 < 16; ++q4) {
            float4 w = wr[q4];
            acc += w.x * shMs[q4*4+0] + w.y * shMs[q4*4+1]
                 + w.z * shMs[q4*4+2] + w.w * shMs[q4*4+3];
        }
        float ret = (acc + (float)kN * bue[d]) * (1.0f / 64.0f);
        shN[d] = ret;
        lsum += ret; lsq += ret * ret;
    }
    #pragma unroll
    for (int m = 1; m < 64; m <<= 1) {
        lsum += __shfl_xor(lsum, m);
        lsq  += __shfl_xor(lsq, m);
    }
    if ((t & 63) == 0) { redLN[t >> 6] = lsum; redLN[4 + (t >> 6)] = lsq; }
    __syncthreads();
    if (t == 0) {
        float s0 = redLN[0] + redLN[1] + redLN[2] + redLN[3];
        float s1 = redLN[4] + redLN[5] + redLN[6] + redLN[7];
        float mu = s0 / (float)kD;
        float var = s1 / (float)kD - mu * mu;
        s_mu = mu;
        s_rs = rsqrtf(var + 1e-5f);
    }
    __syncthreads();
    {
        float mu = s_mu, rs = s_rs;
        for (int d = t; d < kD; d += 256)
            shN[d] = (shN[d] - mu) * rs * ln_g[d] + ln_b[d];
    }
    __syncthreads();

    {
        const int d = s * 64 + (t >> 2);
        const int q = t & 3;
        const float4* wr = (const float4*)(Wo + d * kD + q * 128);
        const float4* nr = (const float4*)(shN + q * 128);
        float acc = 0.f;
        #pragma unroll
        for (int i = 0; i < 32; ++i) {
            float4 w = wr[i]; float4 nv = nr[i];
            acc += w.x*nv.x + w.y*nv.y + w.z*nv.z + w.w*nv.w;
        }
        acc += __shfl_xor(acc, 1);
        acc += __shfl_xor(acc, 2);
        if (q == 0) out[b * kD + d] = acc + bo[d];
    }
}

extern "C" void kernel_launch(void* const* d_in, const int* in_sizes, int n_in,
                              void* d_out, int out_size, void* d_ws, size_t ws_size,
                              hipStream_t stream) {
    const float* keys   = (const float*)d_in[0];
    const float* values = (const float*)d_in[1];
    const float* query  = (const float*)d_in[2];
    const float* Wbk    = (const float*)d_in[3];
    const float* bbk    = (const float*)d_in[4];
    const float* Wbv    = (const float*)d_in[5];
    const float* bbv    = (const float*)d_in[6];
    const float* Wbc    = (const float*)d_in[7];
    const float* bbc    = (const float*)d_in[8];
    const float* Wuq    = (const float*)d_in[9];
    const float* buq    = (const float*)d_in[10];
    const float* Wue    = (const float*)d_in[11];
    const float* bue    = (const float*)d_in[12];
    const float* ln_g   = (const float*)d_in[13];
    const float* ln_b   = (const float*)d_in[14];
    const float* Wo     = (const float*)d_in[15];
    const float* bo     = (const float*)d_in[16];

    // ws layout: S (2 KB) | wsk (64 KB) | wsv (64 KB) | kp (8.4 MB) | vp (8.4 MB)
    float*  Sacc = (float*)d_ws;
    __bf16* wsk  = (__bf16*)((char*)d_ws + 2048);
    __bf16* wsv  = wsk + kBD * kD;
    float*  kp   = (float*)((char*)d_ws + 2048 + 2 * kBD * kD * sizeof(__bf16));
    float*  vp   = kp + (size_t)kB * kN * kBD;
    float*  out  = (float*)d_out;

    lbm_prep<<<dim3(33), dim3(256), 0, stream>>>(Wbk, Wbv, wsk, wsv, Sacc);
    lbm_proj<<<dim3(512), dim3(1024), 0, stream>>>(keys, values, wsk, wsv,
                                                   bbk, bbv, kp, vp);
    lbm_comb<<<dim3(512), dim3(256), 0, stream>>>(kp, vp, Sacc);
    lbm_tail<<<dim3(kB * 8), dim3(256), 0, stream>>>(Sacc, query, Wbc, bbc, Wuq, buq,
                                                     Wue, bue, ln_g, ln_b, Wo, bo, out);
}

// Round 16
// 53.945 us; speedup vs baseline: 1.1547x; 1.1547x over previous
//
#include <hip/hip_runtime.h>
#include <hip/hip_bf16.h>

typedef __bf16 bf16x8 __attribute__((ext_vector_type(8)));
typedef __bf16 bf16x4 __attribute__((ext_vector_type(4)));
typedef float  f32x4  __attribute__((ext_vector_type(4)));

constexpr int kD  = 512;
constexpr int kBD = 64;
constexpr int kN  = 4096;
constexpr int kB  = 8;

__device__ __forceinline__ bf16x8 cvt8v(f32x4 a, f32x4 b) {
    bf16x8 r;
    r[0] = (__bf16)a[0]; r[1] = (__bf16)a[1]; r[2] = (__bf16)a[2]; r[3] = (__bf16)a[3];
    r[4] = (__bf16)b[0]; r[5] = (__bf16)b[1]; r[6] = (__bf16)b[2]; r[7] = (__bf16)b[3];
    return r;
}

// Prep: Wbk/Wbv fp32 -> bf16 ws images (blocks 0..31); block 32 zeroes S.
__global__ __launch_bounds__(256)
void lbm_prep(const float* __restrict__ Wbk, const float* __restrict__ Wbv,
              __bf16* __restrict__ wsk, __bf16* __restrict__ wsv,
              float* __restrict__ S)
{
    const int bid = blockIdx.x, t = threadIdx.x;
    if (bid < 32) {
        int i = (bid * 256 + t) * 4;
        float4 a = *(const float4*)(Wbk + i);
        float4 b = *(const float4*)(Wbv + i);
        bf16x4 ka, vb;
        ka[0]=(__bf16)a.x; ka[1]=(__bf16)a.y; ka[2]=(__bf16)a.z; ka[3]=(__bf16)a.w;
        vb[0]=(__bf16)b.x; vb[1]=(__bf16)b.y; vb[2]=(__bf16)b.z; vb[3]=(__bf16)b.w;
        *(bf16x4*)(wsk + i) = ka;
        *(bf16x4*)(wsv + i) = vb;
    } else {
        S[t * 2] = 0.f; S[t * 2 + 1] = 0.f;
    }
}

// S[b,j] = sum_n (keys[b,n,:].Wbk[j,:] + bbk[j]) * (values[b,n,:].Wbv[j,:] + bbv[j])
//
// R11 (verified) with the prefetch pipeline deepened 4 -> 8 slots: 16
// global_load_dwordx4 in flight per thread = 256 B/thread = 128 KB/CU --
// the in-flight level at which the R10 probe saturated the memory system
// (Little's law: BW = inflight/latency; occupancy/sync/path proved
// irrelevant across R1-R15 except through this variable).
// Weights in 128 KB swizzled LDS (staged once); no main-loop barriers.
__global__ __launch_bounds__(512, 2)
void lbm_bind(const float* __restrict__ keys, const float* __restrict__ values,
              const __bf16* __restrict__ wsk, const __bf16* __restrict__ wsv,
              const float* __restrict__ bbk,  const float* __restrict__ bbv,
              float* __restrict__ S)
{
    __shared__ __bf16 ldsW[2][kBD * kD];   // [K/V][64 j][512 d] swizzled = 128 KB

    const int tid = threadIdx.x;
    const int w   = tid >> 6;
    const int ln  = tid & 63;
    const int l15 = ln & 15;
    const int lhi = ln >> 4;
    const int sw7 = l15 & 7;

    // XCD-aware bijective swizzle: 256 blocks, 8 XCDs -> 32 contiguous each
    const int bid  = blockIdx.x;
    const int swzb = (bid & 7) * 32 + (bid >> 3);
    const int blockRow0 = swzb * 128;
    const int row0 = blockRow0 + w * 16;       // this wave's private 16 rows

    const float* kbase = keys   + (size_t)(row0 + l15) * kD + lhi * 8;
    const float* vbase = values + (size_t)(row0 + l15) * kD + lhi * 8;

#define GLD2X(ra, rb, base_, off_)                                            \
    asm volatile("global_load_dwordx4 %0, %2, off offset:%c3\n\t"             \
                 "global_load_dwordx4 %1, %2, off offset:%c4"                 \
                 : "=v"(ra), "=v"(rb)                                         \
                 : "v"(base_), "i"(off_), "i"((off_) + 16));
#define WAITN(n_, r0, r1, r2, r3)                                             \
    asm volatile("s_waitcnt vmcnt(%c4)"                                       \
                 : "+v"(r0), "+v"(r1), "+v"(r2), "+v"(r3) : "i"(n_));

    f32x4 ka[8], kb2[8], va[8], vb2[8];
    // prologue: 8 steps (32 loads, 256 B/thread) in flight under weight staging
    #pragma unroll
    for (int i = 0; i < 8; ++i) {
        GLD2X(ka[i], kb2[i], kbase, i * 128)
        GLD2X(va[i], vb2[i], vbase, i * 128)
    }

    // ---- stage both weight images into swizzled LDS (once per block) ----
    #pragma unroll
    for (int i = 0; i < 8; ++i) {
        int G = i * 512 + tid;                 // granule 0..4095
        int j = G >> 6, c = G & 63;
        int dst = j * kD + ((c ^ (j & 7)) << 3);
        *(bf16x8*)&ldsW[0][dst] = *(const bf16x8*)(wsk + G * 8);
        *(bf16x8*)&ldsW[1][dst] = *(const bf16x8*)(wsv + G * 8);
    }

    float bk[4], bv[4];
    #pragma unroll
    for (int jt = 0; jt < 4; ++jt) {
        bk[jt] = bbk[jt * 16 + l15];
        bv[jt] = bbv[jt * 16 + l15];
    }

    __syncthreads();   // weights resident (one-time drain; pipeline refills)

    f32x4 kacc[4], vacc[4];
    #pragma unroll
    for (int jt = 0; jt < 4; ++jt) {
        kacc[jt][0]=0.f; kacc[jt][1]=0.f; kacc[jt][2]=0.f; kacc[jt][3]=0.f;
        vacc[jt][0]=0.f; vacc[jt][1]=0.f; vacc[jt][2]=0.f; vacc[jt][3]=0.f;
    }

    // step s: d-range [s*32, s*32+32); slot = s&7; counted vmcnt, no barriers.
    // 4 loads/step -> steady-state wait 28 (7 steps x 4 in flight behind).
#define STEP(s_, n_)                                                          \
    {                                                                         \
        WAITN(n_, ka[(s_) & 7], kb2[(s_) & 7], va[(s_) & 7], vb2[(s_) & 7])   \
        bf16x8 ak_ = cvt8v(ka[(s_) & 7], kb2[(s_) & 7]);                      \
        bf16x8 av_ = cvt8v(va[(s_) & 7], vb2[(s_) & 7]);                      \
        if ((s_) + 8 < 16) {                                                  \
            GLD2X(ka[(s_) & 7], kb2[(s_) & 7], kbase, ((s_) + 8) * 128)       \
            GLD2X(va[(s_) & 7], vb2[(s_) & 7], vbase, ((s_) + 8) * 128)       \
        }                                                                     \
        const int go_ = (((s_) * 4 + lhi) ^ sw7) << 3;                        \
        _Pragma("unroll")                                                     \
        for (int jt = 0; jt < 4; ++jt) {                                      \
            bf16x8 fk_ = *(const bf16x8*)&ldsW[0][(jt * 16 + l15) * kD + go_];\
            bf16x8 fv_ = *(const bf16x8*)&ldsW[1][(jt * 16 + l15) * kD + go_];\
            kacc[jt] = __builtin_amdgcn_mfma_f32_16x16x32_bf16(ak_, fk_, kacc[jt], 0, 0, 0); \
            vacc[jt] = __builtin_amdgcn_mfma_f32_16x16x32_bf16(av_, fv_, vacc[jt], 0, 0, 0); \
        }                                                                     \
    }

    STEP(0, 28)  STEP(1, 28)  STEP(2, 28)  STEP(3, 28)
    STEP(4, 28)  STEP(5, 28)  STEP(6, 28)  STEP(7, 28)
    STEP(8, 28)  STEP(9, 24)  STEP(10, 20) STEP(11, 16)
    STEP(12, 12) STEP(13, 8)  STEP(14, 4)  STEP(15, 0)
#undef STEP
#undef WAITN
#undef GLD2X

    // combine: lane holds C col j = jt*16+l15, rows (lhi*4+i) -- rows sum away
    #pragma unroll
    for (int jt = 0; jt < 4; ++jt) {
        float sreg = 0.0f;
        #pragma unroll
        for (int i = 0; i < 4; ++i)
            sreg += (kacc[jt][i] + bk[jt]) * (vacc[jt][i] + bv[jt]);
        sreg += __shfl_xor(sreg, 16);
        sreg += __shfl_xor(sreg, 32);
        if (lhi == 0) {
            int bidx = blockRow0 >> 12;   // / kN
            atomicAdd(&S[bidx * kBD + jt * 16 + l15], sreg);
        }
    }
}

// Fused tail: 64 blocks; each block redundantly computes S->Bsum->ms->ext->LN
// for its batch b, then its 64-wide slice of out = normed.Wo^T + bo.
__global__ __launch_bounds__(256)
void lbm_tail(const float* __restrict__ S,    const float* __restrict__ query,
              const float* __restrict__ Wbc,  const float* __restrict__ bbc,
              const float* __restrict__ Wuq,  const float* __restrict__ buq,
              const float* __restrict__ Wue,  const float* __restrict__ bue,
              const float* __restrict__ ln_g, const float* __restrict__ ln_b,
              const float* __restrict__ Wo,   const float* __restrict__ bo,
              float* __restrict__ out)
{
    const int b = blockIdx.x >> 3;
    const int s = blockIdx.x & 7;
    const int t = threadIdx.x;

    __shared__ float shS[kBD];
    __shared__ float shB[kD];
    __shared__ float shMs[kBD];
    __shared__ float shN[kD];
    __shared__ float redT[4][kBD];
    __shared__ float redQ[4][kBD];
    __shared__ float redLN[8];
    __shared__ float s_mu, s_rs;

    if (t < kBD) shS[t] = S[b * kBD + t];
    __syncthreads();

    for (int d = t; d < kD; d += 256) {
        const float4* wr = (const float4*)(Wbc + d * kBD);
        float acc = 0.f;
        #pragma unroll
        for (int q4 = 0; q4 < 16; ++q4) {
            float4 w = wr[q4];
            acc += w.x * shS[q4*4+0] + w.y * shS[q4*4+1]
                 + w.z * shS[q4*4+2] + w.w * shS[q4*4+3];
        }
        shB[d] = acc + (float)kN * bbc[d];
    }
    __syncthreads();

    {
        const int jj = t & 63, qq = t >> 6;
        const float4* wr = (const float4*)(Wuq + jj * kD + qq * 128);
        const float4* qr = (const float4*)(query + b * kD + qq * 128);
        const float4* br = (const float4*)(shB + qq * 128);
        float at = 0.f, aq = 0.f;
        #pragma unroll
        for (int i = 0; i < 32; ++i) {
            float4 w = wr[i]; float4 bb = br[i]; float4 qv = qr[i];
            at += w.x*bb.x + w.y*bb.y + w.z*bb.z + w.w*bb.w;
            aq += w.x*qv.x + w.y*qv.y + w.z*qv.z + w.w*qv.w;
        }
        redT[qq][jj] = at; redQ[qq][jj] = aq;
    }
    __syncthreads();
    if (t < kBD) {
        float tv = redT[0][t] + redT[1][t] + redT[2][t] + redT[3][t] + (float)kN * buq[t];
        float qv = redQ[0][t] + redQ[1][t] + redQ[2][t] + redQ[3][t] + buq[t];
        shMs[t] = tv * qv;
    }
    __syncthreads();

    float lsum = 0.f, lsq = 0.f;
    for (int d = t; d < kD; d += 256) {
        const float4* wr = (const float4*)(Wue + d * kBD);
        float acc = 0.f;
        #pragma unroll
        for (int q4 = 0; q4 < 16; ++q4) {
            float4 w = wr[q4];
            acc += w.x * shMs[q4*4+0] + w.y * shMs[q4*4+1]
                 + w.z * shMs[q4*4+2] + w.w * shMs[q4*4+3];
        }
        float ret = (acc + (float)kN * bue[d]) * (1.0f / 64.0f);
        shN[d] = ret;
        lsum += ret; lsq += ret * ret;
    }
    #pragma unroll
    for (int m = 1; m < 64; m <<= 1) {
        lsum += __shfl_xor(lsum, m);
        lsq  += __shfl_xor(lsq, m);
    }
    if ((t & 63) == 0) { redLN[t >> 6] = lsum; redLN[4 + (t >> 6)] = lsq; }
    __syncthreads();
    if (t == 0) {
        float s0 = redLN[0] + redLN[1] + redLN[2] + redLN[3];
        float s1 = redLN[4] + redLN[5] + redLN[6] + redLN[7];
        float mu = s0 / (float)kD;
        float var = s1 / (float)kD - mu * mu;
        s_mu = mu;
        s_rs = rsqrtf(var + 1e-5f);
    }
    __syncthreads();
    {
        float mu = s_mu, rs = s_rs;
        for (int d = t; d < kD; d += 256)
            shN[d] = (shN[d] - mu) * rs * ln_g[d] + ln_b[d];
    }
    __syncthreads();

    {
        const int d = s * 64 + (t >> 2);
        const int q = t & 3;
        const float4* wr = (const float4*)(Wo + d * kD + q * 128);
        const float4* nr = (const float4*)(shN + q * 128);
        float acc = 0.f;
        #pragma unroll
        for (int i = 0; i < 32; ++i) {
            float4 w = wr[i]; float4 nv = nr[i];
            acc += w.x*nv.x + w.y*nv.y + w.z*nv.z + w.w*nv.w;
        }
        acc += __shfl_xor(acc, 1);
        acc += __shfl_xor(acc, 2);
        if (q == 0) out[b * kD + d] = acc + bo[d];
    }
}

extern "C" void kernel_launch(void* const* d_in, const int* in_sizes, int n_in,
                              void* d_out, int out_size, void* d_ws, size_t ws_size,
                              hipStream_t stream) {
    const float* keys   = (const float*)d_in[0];
    const float* values = (const float*)d_in[1];
    const float* query  = (const float*)d_in[2];
    const float* Wbk    = (const float*)d_in[3];
    const float* bbk    = (const float*)d_in[4];
    const float* Wbv    = (const float*)d_in[5];
    const float* bbv    = (const float*)d_in[6];
    const float* Wbc    = (const float*)d_in[7];
    const float* bbc    = (const float*)d_in[8];
    const float* Wuq    = (const float*)d_in[9];
    const float* buq    = (const float*)d_in[10];
    const float* Wue    = (const float*)d_in[11];
    const float* bue    = (const float*)d_in[12];
    const float* ln_g   = (const float*)d_in[13];
    const float* ln_b   = (const float*)d_in[14];
    const float* Wo     = (const float*)d_in[15];
    const float* bo     = (const float*)d_in[16];

    // ws layout: S[8][64] f32 (2 KB) | wsk (64 KB) | wsv (64 KB)
    float*  Sacc = (float*)d_ws;
    __bf16* wsk  = (__bf16*)((char*)d_ws + 2048);
    __bf16* wsv  = wsk + kBD * kD;
    float*  out  = (float*)d_out;

    lbm_prep<<<dim3(33), dim3(256), 0, stream>>>(Wbk, Wbv, wsk, wsv, Sacc);

    const int nblocks = (kB * kN) / 128;   // 256 blocks x 512 threads, 1 block/CU
    lbm_bind<<<dim3(nblocks), dim3(512), 0, stream>>>(keys, values, wsk, wsv,
                                                      bbk, bbv, Sacc);
    lbm_tail<<<dim3(kB * 8), dim3(256), 0, stream>>>(Sacc, query, Wbc, bbc, Wuq, buq,
                                                     Wue, bue, ln_g, ln_b, Wo, bo, out);
}